// Round 4
// baseline (634.092 us; speedup 1.0000x reference)
//
#include <hip/hip_runtime.h>

// Problem constants (B, C, H, W = 64, 2048, 24, 8; NUM_IDS = 751)
#define BB 64
#define CC 2048
#define HWN 192              // H*W
#define HW4 48               // HW in float4
#define CCHUNK 64            // channels per block
#define NCHUNK (CC / CCHUNK) // 32 chunks per sample
#define CITER (CCHUNK / 4)   // 16 c-iterations per thread (thread owns c = cl + 4*i)
#define MAGIC 0x5CA1AB1Eu

// Fused single kernel:
//   phase 1: partial heat for chunk (b,k); features cached in registers
//   flag barrier across the sample's 32 chunk-blocks (device-scope atomics)
//   phase 2: redundant per-block reduce + min/max normalize
//   phase 3: scale register-cached features, stream out
// grid = 2048 (b*32 + k), block = 192. thread -> (cl = tid/48, hw4 = tid%48).
__global__ void __launch_bounds__(192, 3) fused_kernel(
    const float* __restrict__ f,
    const float* __restrict__ w,
    const int* __restrict__ pids,
    float* __restrict__ out,
    float* __restrict__ partial,
    unsigned int* __restrict__ flags)
{
    const int blk = blockIdx.x;
    const int b = blk >> 5;             // / NCHUNK
    const int k = blk & (NCHUNK - 1);   // % NCHUNK
    const int tid = threadIdx.x;        // 0..191
    const int hw4 = tid % HW4;          // 0..47
    const int cl  = tid / HW4;          // 0..3

    __shared__ float ws[CCHUNK];
    __shared__ __align__(16) float4 red[HWN];  // float4 reduce scratch / scalar scratch
    __shared__ __align__(16) float hl[HWN];    // normalized heat for sample b
    __shared__ float s_mn, s_mx;

    const int row = pids[b];
    if (tid < CCHUNK) ws[tid] = w[(size_t)row * CC + k * CCHUNK + tid];
    __syncthreads();

    // ---- Phase 1: load features once into registers, partial heat ----
    const size_t base = ((size_t)b * CC + (size_t)k * CCHUNK) * HW4;  // float4 units
    const float4* fb4 = (const float4*)f + base;

    float4 r[CITER];
#pragma unroll
    for (int i = 0; i < CITER; ++i)
        r[i] = fb4[(size_t)(cl + 4 * i) * HW4 + hw4];

    float4 acc = make_float4(0.f, 0.f, 0.f, 0.f);
#pragma unroll
    for (int i = 0; i < CITER; ++i) {
        const float wv = ws[cl + 4 * i];
        acc.x = fmaf(wv, r[i].x, acc.x);
        acc.y = fmaf(wv, r[i].y, acc.y);
        acc.z = fmaf(wv, r[i].z, acc.z);
        acc.w = fmaf(wv, r[i].w, acc.w);
    }
    red[tid] = acc;
    __syncthreads();
    if (tid < HW4) {
        float4 a0 = red[tid], a1 = red[tid + 48], a2 = red[tid + 96], a3 = red[tid + 144];
        float4 s = make_float4(a0.x + a1.x + a2.x + a3.x,
                               a0.y + a1.y + a2.y + a3.y,
                               a0.z + a1.z + a2.z + a3.z,
                               a0.w + a1.w + a2.w + a3.w);
        ((float4*)partial)[(size_t)(b * NCHUNK + k) * HW4 + tid] = s;
    }
    // release own flag: per-thread fence, block barrier, then one release store
    __threadfence();
    __syncthreads();
    if (tid == 0)
        __hip_atomic_store(&flags[b * NCHUNK + k], MAGIC,
                           __ATOMIC_RELEASE, __HIP_MEMORY_SCOPE_AGENT);

    // ---- flag barrier: wait for all 32 chunks of sample b ----
    if (tid < NCHUNK) {
        while (__hip_atomic_load(&flags[b * NCHUNK + tid],
                                 __ATOMIC_ACQUIRE, __HIP_MEMORY_SCOPE_AGENT) != MAGIC)
            __builtin_amdgcn_s_sleep(2);
    }
    __syncthreads();
    __threadfence();

    // ---- Phase 2: reduce 32 partial chunks + min/max normalize ----
    float v = 0.f;
    {
        const float* pb = partial + (size_t)b * NCHUNK * HWN + tid;
#pragma unroll
        for (int kk = 0; kk < NCHUNK; ++kk)
            v += pb[(size_t)kk * HWN];
    }
    float* scratch = (float*)red;
    scratch[tid] = v;
    __syncthreads();
    if (tid < 64) {
        float m0 = scratch[tid], m1 = scratch[tid + 64], m2 = scratch[tid + 128];
        float mn = fminf(m0, fminf(m1, m2));
        float mx = fmaxf(m0, fmaxf(m1, m2));
        for (int off = 32; off > 0; off >>= 1) {
            mn = fminf(mn, __shfl_down(mn, off));
            mx = fmaxf(mx, __shfl_down(mx, off));
        }
        if (tid == 0) { s_mn = mn; s_mx = mx; }
    }
    __syncthreads();
    {
        const float mn = s_mn, mx = s_mx;
        // reference: normalize only if max != 0
        hl[tid] = (mx != 0.f) ? (v - mn) / (mx - mn) : v;
    }
    __syncthreads();

    // ---- Phase 3: scale register-cached features, stream out ----
    const float4 hv = ((const float4*)hl)[hw4];
    float4* ob4 = (float4*)out + base;
#pragma unroll
    for (int i = 0; i < CITER; ++i) {
        float4 x = r[i];
        x.x *= hv.x; x.y *= hv.y; x.z *= hv.z; x.w *= hv.w;
        ob4[(size_t)(cl + 4 * i) * HW4 + hw4] = x;
    }
}

extern "C" void kernel_launch(void* const* d_in, const int* in_sizes, int n_in,
                              void* d_out, int out_size, void* d_ws, size_t ws_size,
                              hipStream_t stream) {
    const float* features = (const float*)d_in[0];   // [64,2048,24,8] f32
    const float* weight   = (const float*)d_in[1];   // [751,2048] f32
    const int*   pids     = (const int*)d_in[2];     // [64] int
    float* out = (float*)d_out;                      // [64,2048,24,8] f32

    float* partial = (float*)d_ws;                            // 64*32*192 floats
    unsigned int* flags = (unsigned int*)(partial + (size_t)BB * NCHUNK * HWN); // 2048 u32

    fused_kernel<<<BB * NCHUNK, HWN, 0, stream>>>(features, weight, pids, out,
                                                  partial, flags);
}